// Round 1
// baseline (22457.391 us; speedup 1.0000x reference)
//
#include <hip/hip_runtime.h>
#include <math.h>

// NeuralStateSpace: h_{t+1} = tanh(h_t @ A_w^T + A_b + x_t @ B_w^T + B_b), then LN + head.
// One workgroup per batch element (256 blocks = 256 CUs). Weights in registers,
// h double-buffered in LDS, x streamed in chunks with register prefetch.

#define S_LEN   4096
#define I_DIM   64
#define H_DIM   128
#define T_CHUNK 128
#define NCHUNK  (S_LEN / T_CHUNK)   // 32
#define NTHR    512

__global__ __launch_bounds__(NTHR, 1)
void nss_scan_kernel(const float* __restrict__ x,
                     const float* __restrict__ A_w,
                     const float* __restrict__ A_b,
                     const float* __restrict__ B_w,
                     const float* __restrict__ B_b,
                     const float* __restrict__ ln_g,
                     const float* __restrict__ ln_b,
                     const float* __restrict__ head_w,
                     const float* __restrict__ head_b,
                     float* __restrict__ out)
{
    __shared__ float xs[2][T_CHUNK * I_DIM];  // 64 KiB: double-buffered x chunks
    __shared__ float hb[2][H_DIM];            // 1 KiB:  double-buffered hidden state
    __shared__ float pad[5120];               // 20 KiB: force 1 block/CU (total >80KiB)

    const int t = threadIdx.x;
    const int b = blockIdx.x;
    const int r = t >> 2;   // output row 0..127
    const int q = t & 3;    // quarter 0..3 of the dot product

    if (b == 0x7fffffff) pad[t] = 0.f;  // keep pad alive (never true)

    // ---- load this thread's weight slices into registers (one-time) ----
    float4 ar[8];  // A_w[r][q*32 .. q*32+31]
    float4 br[4];  // B_w[r][q*16 .. q*16+15]
    {
        const float4* Ap = (const float4*)(A_w + r * H_DIM + q * 32);
#pragma unroll
        for (int j = 0; j < 8; ++j) ar[j] = Ap[j];
        const float4* Bp = (const float4*)(B_w + r * I_DIM + q * 16);
#pragma unroll
        for (int j = 0; j < 4; ++j) br[j] = Bp[j];
    }
    const float bias = A_b[r] + B_b[r];

    if (t < H_DIM) hb[0][t] = 0.f;  // h0 = 0

    const float* xb = x + (size_t)b * S_LEN * I_DIM;

    // prologue: stage chunk 0
    {
        const float4* g = (const float4*)xb;
        float4* d = (float4*)(xs[0]);
#pragma unroll
        for (int rr = 0; rr < 4; ++rr) d[rr * NTHR + t] = g[rr * NTHR + t];
    }
    __syncthreads();

    float4 nx[4];
    for (int c = 0; c < NCHUNK; ++c) {
        const int cur = c & 1;
        // issue next chunk's global loads early (latency hides under compute)
        if (c + 1 < NCHUNK) {
            const float4* g = (const float4*)(xb + (c + 1) * T_CHUNK * I_DIM);
#pragma unroll
            for (int rr = 0; rr < 4; ++rr) nx[rr] = g[rr * NTHR + t];
        }

#pragma unroll 2
        for (int ss = 0; ss < T_CHUNK; ++ss) {
            const int s = c * T_CHUNK + ss;
            const int p = s & 1;
            const float* hrow = hb[p];
            const float* xrow = xs[cur] + ss * I_DIM;

            float acc = 0.f;
            // A-part: 32 MACs against h, quarter-staggered to avoid bank conflicts
#pragma unroll
            for (int k = 0; k < 8; ++k) {
                const int blk = (k + 2 * q) & 7;
                const float4 hv = *(const float4*)(hrow + q * 32 + blk * 4);
                const float4 av = ar[blk];
                acc += av.x * hv.x + av.y * hv.y + av.z * hv.z + av.w * hv.w;
            }
            // B-part: 16 MACs against x_t
#pragma unroll
            for (int k = 0; k < 4; ++k) {
                const int blk = (k + q) & 3;
                const float4 xv = *(const float4*)(xrow + q * 16 + blk * 4);
                const float4 bv = br[blk];
                acc += bv.x * xv.x + bv.y * xv.y + bv.z * xv.z + bv.w * xv.w;
            }
            // combine the 4 quarter-dots (lanes 4k..4k+3, same wave)
            acc += __shfl_xor(acc, 1);
            acc += __shfl_xor(acc, 2);
            if (q == 0) {
                const float y = acc + bias;
                const float xc = fminf(9.f, fmaxf(-9.f, y));
                const float e = __expf(2.f * xc);
                hb[p ^ 1][r] = __fdividef(e - 1.f, e + 1.f);  // tanh(y)
            }
            __syncthreads();
        }

        // write prefetched chunk into the idle buffer
        if (c + 1 < NCHUNK) {
            float4* d = (float4*)(xs[cur ^ 1]);
#pragma unroll
            for (int rr = 0; rr < 4; ++rr) d[rr * NTHR + t] = nx[rr];
            __syncthreads();
        }
    }

    // ---- epilogue: LayerNorm + head (final h is in hb[0], S even) ----
    if (t < 64) {
        const float a  = hb[0][t];
        const float c2 = hb[0][t + 64];
        float sum = a + c2;
#pragma unroll
        for (int o = 32; o > 0; o >>= 1) sum += __shfl_xor(sum, o);
        const float mu = sum * (1.f / 128.f);
        const float d1 = a - mu, d2 = c2 - mu;
        float sq = d1 * d1 + d2 * d2;
#pragma unroll
        for (int o = 32; o > 0; o >>= 1) sq += __shfl_xor(sq, o);
        const float rs = rsqrtf(sq * (1.f / 128.f) + 1e-5f);
        const float hn1 = d1 * rs * ln_g[t] + ln_b[t];
        const float hn2 = d2 * rs * ln_g[t + 64] + ln_b[t + 64];
        float contrib = hn1 * head_w[t] + hn2 * head_w[t + 64];
#pragma unroll
        for (int o = 32; o > 0; o >>= 1) contrib += __shfl_xor(contrib, o);
        if (t == 0) out[b] = contrib + head_b[0];
    }
}

extern "C" void kernel_launch(void* const* d_in, const int* in_sizes, int n_in,
                              void* d_out, int out_size, void* d_ws, size_t ws_size,
                              hipStream_t stream)
{
    const float* x      = (const float*)d_in[0];
    const float* A_w    = (const float*)d_in[1];
    const float* A_b    = (const float*)d_in[2];
    const float* B_w    = (const float*)d_in[3];
    const float* B_b    = (const float*)d_in[4];
    const float* ln_g   = (const float*)d_in[5];
    const float* ln_b   = (const float*)d_in[6];
    const float* head_w = (const float*)d_in[7];
    const float* head_b = (const float*)d_in[8];
    float* out = (float*)d_out;

    const int Bsz = in_sizes[0] / (S_LEN * I_DIM);  // 256
    nss_scan_kernel<<<Bsz, NTHR, 0, stream>>>(x, A_w, A_b, B_w, B_b,
                                              ln_g, ln_b, head_w, head_b, out);
}

// Round 2
// 2003.170 us; speedup vs baseline: 11.2109x; 11.2109x over previous
//
#include <hip/hip_runtime.h>
#include <math.h>

// NeuralStateSpace: h_{t+1} = tanh(h_t @ A_w^T + A_b + x_t @ B_w^T + B_b), then LN + head.
// One workgroup per batch element (256 blocks = 256 CUs). Weights in registers
// (COMPILE-TIME indexed — runtime indexing sends arrays to scratch, rule #20),
// h double-buffered in LDS, x streamed in chunks with register prefetch.
// Bank-conflict stagger is baked in at weight-LOAD time so the per-step register
// index is the plain loop constant k while the LDS address is q-staggered.

#define S_LEN   4096
#define I_DIM   64
#define H_DIM   128
#define T_CHUNK 128
#define NCHUNK  (S_LEN / T_CHUNK)   // 32
#define NTHR    512
#define XS_PAD  3072                // pad LDS > 80 KiB => exactly 1 block/CU

__device__ __forceinline__ float dot4(float4 a, float4 b) {
    return a.x * b.x + a.y * b.y + a.z * b.z + a.w * b.w;
}

__global__ __launch_bounds__(NTHR, 2)
void nss_scan_kernel(const float* __restrict__ x,
                     const float* __restrict__ A_w,
                     const float* __restrict__ A_b,
                     const float* __restrict__ B_w,
                     const float* __restrict__ B_b,
                     const float* __restrict__ ln_g,
                     const float* __restrict__ ln_b,
                     const float* __restrict__ head_w,
                     const float* __restrict__ head_b,
                     float* __restrict__ out)
{
    __shared__ float xs[2][T_CHUNK * I_DIM + XS_PAD]; // ~90 KiB total: double-buffered x
    __shared__ float hb[2][H_DIM];                    // double-buffered hidden state

    const int t = threadIdx.x;
    const int b = blockIdx.x;
    const int r = t >> 2;   // output row 0..127
    const int q = t & 3;    // quarter 0..3 of the dot product

    // ---- weight slices into registers; stagger baked into LOAD address ----
    // use-time LDS byte offset for A chunk k: q*128 + ((k+2q)&7)*16  (bank-disjoint across q)
    float4 ar0, ar1, ar2, ar3, ar4, ar5, ar6, ar7;
    float4 br0, br1, br2, br3;
    {
        const float* Ap = A_w + r * H_DIM + q * 32;
        ar0 = *(const float4*)(Ap + (((0 + 2 * q) & 7) << 2));
        ar1 = *(const float4*)(Ap + (((1 + 2 * q) & 7) << 2));
        ar2 = *(const float4*)(Ap + (((2 + 2 * q) & 7) << 2));
        ar3 = *(const float4*)(Ap + (((3 + 2 * q) & 7) << 2));
        ar4 = *(const float4*)(Ap + (((4 + 2 * q) & 7) << 2));
        ar5 = *(const float4*)(Ap + (((5 + 2 * q) & 7) << 2));
        ar6 = *(const float4*)(Ap + (((6 + 2 * q) & 7) << 2));
        ar7 = *(const float4*)(Ap + (((7 + 2 * q) & 7) << 2));
        const float* Bp = B_w + r * I_DIM + q * 16;
        br0 = *(const float4*)(Bp + (((0 + q) & 3) << 2));
        br1 = *(const float4*)(Bp + (((1 + q) & 3) << 2));
        br2 = *(const float4*)(Bp + (((2 + q) & 3) << 2));
        br3 = *(const float4*)(Bp + (((3 + q) & 3) << 2));
    }
    const float bias = A_b[r] + B_b[r];

    if (t < H_DIM) hb[0][t] = 0.f;  // h0 = 0

    const float* xb = x + (size_t)b * S_LEN * I_DIM;

    // prologue: stage chunk 0 directly
    {
        const float4* g = (const float4*)xb;
        float4* d = (float4*)(xs[0]);
#pragma unroll
        for (int rr = 0; rr < 4; ++rr) d[rr * NTHR + t] = g[rr * NTHR + t];
    }
    __syncthreads();

    for (int c = 0; c < NCHUNK; ++c) {
        const int cur = c & 1;
        // issue next chunk's global loads early; they land in NAMED registers
        // (first step-barrier drains vmcnt once per chunk — ~1 HBM latency)
        float4 nx0, nx1, nx2, nx3;
        if (c + 1 < NCHUNK) {
            const float4* g = (const float4*)(xb + (c + 1) * T_CHUNK * I_DIM);
            nx0 = g[0 * NTHR + t];
            nx1 = g[1 * NTHR + t];
            nx2 = g[2 * NTHR + t];
            nx3 = g[3 * NTHR + t];
        }

#pragma unroll 2
        for (int ss = 0; ss < T_CHUNK; ++ss) {
            const int s = c * T_CHUNK + ss;
            const int p = s & 1;                        // compile-time under unroll-2
            const char* hrow = (const char*)(hb[p]);
            const char* xrow = (const char*)(xs[cur] + ss * I_DIM);

            float acc;
            // A-part: 32 MACs vs h; LDS address staggered per q, register index static
            {
                const float4 h0 = *(const float4*)(hrow + q * 128 + (((0 + 2 * q) & 7) << 4));
                const float4 h1 = *(const float4*)(hrow + q * 128 + (((1 + 2 * q) & 7) << 4));
                const float4 h2 = *(const float4*)(hrow + q * 128 + (((2 + 2 * q) & 7) << 4));
                const float4 h3 = *(const float4*)(hrow + q * 128 + (((3 + 2 * q) & 7) << 4));
                const float4 h4 = *(const float4*)(hrow + q * 128 + (((4 + 2 * q) & 7) << 4));
                const float4 h5 = *(const float4*)(hrow + q * 128 + (((5 + 2 * q) & 7) << 4));
                const float4 h6 = *(const float4*)(hrow + q * 128 + (((6 + 2 * q) & 7) << 4));
                const float4 h7 = *(const float4*)(hrow + q * 128 + (((7 + 2 * q) & 7) << 4));
                float a0 = dot4(ar0, h0) + dot4(ar1, h1);
                float a1 = dot4(ar2, h2) + dot4(ar3, h3);
                float a2 = dot4(ar4, h4) + dot4(ar5, h5);
                float a3 = dot4(ar6, h6) + dot4(ar7, h7);
                acc = (a0 + a1) + (a2 + a3);
            }
            // B-part: 16 MACs vs x_t, same trick
            {
                const float4 x0 = *(const float4*)(xrow + q * 64 + (((0 + q) & 3) << 4));
                const float4 x1 = *(const float4*)(xrow + q * 64 + (((1 + q) & 3) << 4));
                const float4 x2 = *(const float4*)(xrow + q * 64 + (((2 + q) & 3) << 4));
                const float4 x3 = *(const float4*)(xrow + q * 64 + (((3 + q) & 3) << 4));
                acc += (dot4(br0, x0) + dot4(br1, x1)) + (dot4(br2, x2) + dot4(br3, x3));
            }
            // combine the 4 quarter-dots (lanes 4k..4k+3, same wave)
            acc += __shfl_xor(acc, 1);
            acc += __shfl_xor(acc, 2);
            // all lanes compute tanh (no divergent branch); q==0 writes
            const float y = acc + bias;
            const float xc = fminf(9.f, fmaxf(-9.f, y));
            const float e = __expf(2.f * xc);
            const float th = __fdividef(e - 1.f, e + 1.f);
            if (q == 0) hb[p ^ 1][r] = th;
            __syncthreads();
        }

        // write prefetched chunk into the idle buffer
        if (c + 1 < NCHUNK) {
            float4* d = (float4*)(xs[cur ^ 1]);
            d[0 * NTHR + t] = nx0;
            d[1 * NTHR + t] = nx1;
            d[2 * NTHR + t] = nx2;
            d[3 * NTHR + t] = nx3;
            __syncthreads();
        }
    }

    // ---- epilogue: LayerNorm + head (final h is in hb[0], S even) ----
    if (t < 64) {
        const float a  = hb[0][t];
        const float c2 = hb[0][t + 64];
        float sum = a + c2;
#pragma unroll
        for (int o = 32; o > 0; o >>= 1) sum += __shfl_xor(sum, o);
        const float mu = sum * (1.f / 128.f);
        const float d1 = a - mu, d2 = c2 - mu;
        float sq = d1 * d1 + d2 * d2;
#pragma unroll
        for (int o = 32; o > 0; o >>= 1) sq += __shfl_xor(sq, o);
        const float rs = rsqrtf(sq * (1.f / 128.f) + 1e-5f);
        const float hn1 = d1 * rs * ln_g[t] + ln_b[t];
        const float hn2 = d2 * rs * ln_g[t + 64] + ln_b[t + 64];
        float contrib = hn1 * head_w[t] + hn2 * head_w[t + 64];
#pragma unroll
        for (int o = 32; o > 0; o >>= 1) contrib += __shfl_xor(contrib, o);
        if (t == 0) out[b] = contrib + head_b[0];
    }
}

extern "C" void kernel_launch(void* const* d_in, const int* in_sizes, int n_in,
                              void* d_out, int out_size, void* d_ws, size_t ws_size,
                              hipStream_t stream)
{
    const float* x      = (const float*)d_in[0];
    const float* A_w    = (const float*)d_in[1];
    const float* A_b    = (const float*)d_in[2];
    const float* B_w    = (const float*)d_in[3];
    const float* B_b    = (const float*)d_in[4];
    const float* ln_g   = (const float*)d_in[5];
    const float* ln_b   = (const float*)d_in[6];
    const float* head_w = (const float*)d_in[7];
    const float* head_b = (const float*)d_in[8];
    float* out = (float*)d_out;

    const int Bsz = in_sizes[0] / (S_LEN * I_DIM);  // 256
    nss_scan_kernel<<<Bsz, NTHR, 0, stream>>>(x, A_w, A_b, B_w, B_b,
                                              ln_g, ln_b, head_w, head_b, out);
}

// Round 3
// 1550.366 us; speedup vs baseline: 14.4852x; 1.2921x over previous
//
#include <hip/hip_runtime.h>
#include <math.h>

// NeuralStateSpace: h_{t+1} = tanh(h_t @ A_w^T + A_b + x_t @ B_w^T + B_b), then LN + head.
// One workgroup per batch element (256 blocks = 256 CUs). Weights in registers,
// pre-scaled by 2*log2(e) so tanh = 1 - 2/(2^acc + 1) with NO clamp (self-saturating).
// Dot products via v_pk_fma_f32 (packed fp32, halves issue). Quad reduction via
// DPP quad_perm (replaces ds_bpermute-based __shfl_xor: ~200 cyc -> ~8 cyc).

#define S_LEN   4096
#define I_DIM   64
#define H_DIM   128
#define T_CHUNK 128
#define NCHUNK  (S_LEN / T_CHUNK)   // 32
#define NTHR    512
#define XS_PAD  3072                // pad LDS > 80 KiB => exactly 1 block/CU

typedef float v2f __attribute__((ext_vector_type(2)));

__device__ __forceinline__ v2f pk_mul(v2f a, v2f b) {
    v2f d;
    asm("v_pk_mul_f32 %0, %1, %2" : "=v"(d) : "v"(a), "v"(b));
    return d;
}
__device__ __forceinline__ v2f pk_fma(v2f a, v2f b, v2f c) {
    v2f d;
    asm("v_pk_fma_f32 %0, %1, %2, %3" : "=v"(d) : "v"(a), "v"(b), "v"(c));
    return d;
}
__device__ __forceinline__ v2f pk_add(v2f a, v2f b) {
    v2f d;
    asm("v_pk_add_f32 %0, %1, %2" : "=v"(d) : "v"(a), "v"(b));
    return d;
}
__device__ __forceinline__ v2f lo4(float4 v) { v2f r; r.x = v.x; r.y = v.y; return r; }
__device__ __forceinline__ v2f hi4(float4 v) { v2f r; r.x = v.z; r.y = v.w; return r; }

// DPP quad_perm swaps (all lanes active): xor1 = [1,0,3,2] = 0xB1, xor2 = [2,3,0,1] = 0x4E
__device__ __forceinline__ float dpp_xor1(float v) {
    int i = __builtin_amdgcn_update_dpp(0, __builtin_bit_cast(int, v), 0xB1, 0xf, 0xf, true);
    return __builtin_bit_cast(float, i);
}
__device__ __forceinline__ float dpp_xor2(float v) {
    int i = __builtin_amdgcn_update_dpp(0, __builtin_bit_cast(int, v), 0x4E, 0xf, 0xf, true);
    return __builtin_bit_cast(float, i);
}
__device__ __forceinline__ float fast_exp2(float x) {
    float r;
    asm("v_exp_f32 %0, %1" : "=v"(r) : "v"(x));
    return r;
}
__device__ __forceinline__ float fast_rcp(float x) {
    float r;
    asm("v_rcp_f32 %0, %1" : "=v"(r) : "v"(x));
    return r;
}

#define KSCALE 2.8853900817779268f   // 2*log2(e)

__global__ __launch_bounds__(NTHR, 2)
void nss_scan_kernel(const float* __restrict__ x,
                     const float* __restrict__ A_w,
                     const float* __restrict__ A_b,
                     const float* __restrict__ B_w,
                     const float* __restrict__ B_b,
                     const float* __restrict__ ln_g,
                     const float* __restrict__ ln_b,
                     const float* __restrict__ head_w,
                     const float* __restrict__ head_b,
                     float* __restrict__ out)
{
    __shared__ float xs[2][T_CHUNK * I_DIM + XS_PAD]; // ~90 KiB total: double-buffered x
    __shared__ float hb[2][H_DIM];                    // double-buffered hidden state

    const int t = threadIdx.x;
    const int b = blockIdx.x;
    const int r = t >> 2;   // output row 0..127
    const int q = t & 3;    // quarter 0..3 of the dot product

    // ---- weight slices into registers (scaled by 2*log2e); q-stagger baked into address ----
    float4 ar0, ar1, ar2, ar3, ar4, ar5, ar6, ar7;
    float4 br0, br1, br2, br3;
    {
        const float* Ap = A_w + r * H_DIM + q * 32;
#define LDA(k) { float4 v = *(const float4*)(Ap + (((k + 2 * q) & 7) << 2)); \
                 v.x *= KSCALE; v.y *= KSCALE; v.z *= KSCALE; v.w *= KSCALE; ar##k = v; }
        LDA(0) LDA(1) LDA(2) LDA(3) LDA(4) LDA(5) LDA(6) LDA(7)
#undef LDA
        const float* Bp = B_w + r * I_DIM + q * 16;
#define LDB(k) { float4 v = *(const float4*)(Bp + (((k + q) & 3) << 2)); \
                 v.x *= KSCALE; v.y *= KSCALE; v.z *= KSCALE; v.w *= KSCALE; br##k = v; }
        LDB(0) LDB(1) LDB(2) LDB(3)
#undef LDB
    }
    const float bias = (A_b[r] + B_b[r]) * KSCALE;

    if (t < H_DIM) hb[0][t] = 0.f;  // h0 = 0

    const float* xb = x + (size_t)b * S_LEN * I_DIM;

    // prologue: stage chunk 0 directly
    {
        const float4* g = (const float4*)xb;
        float4* d = (float4*)(xs[0]);
#pragma unroll
        for (int rr = 0; rr < 4; ++rr) d[rr * NTHR + t] = g[rr * NTHR + t];
    }
    __syncthreads();

    for (int c = 0; c < NCHUNK; ++c) {
        const int cur = c & 1;
        // issue next chunk's global loads early into NAMED registers
        float4 nx0, nx1, nx2, nx3;
        if (c + 1 < NCHUNK) {
            const float4* g = (const float4*)(xb + (c + 1) * T_CHUNK * I_DIM);
            nx0 = g[0 * NTHR + t];
            nx1 = g[1 * NTHR + t];
            nx2 = g[2 * NTHR + t];
            nx3 = g[3 * NTHR + t];
        }

#pragma unroll 2
        for (int ss = 0; ss < T_CHUNK; ++ss) {
            const int p = ss & 1;                       // compile-time under unroll-2
            const char* hrow = (const char*)(hb[p]);
            const char* xrow = (const char*)(xs[cur] + ss * I_DIM);

            // LDS reads: addresses q-staggered (4 distinct addrs/wave -> bank broadcast)
            const float4 h0 = *(const float4*)(hrow + q * 128 + (((0 + 2 * q) & 7) << 4));
            const float4 h1 = *(const float4*)(hrow + q * 128 + (((1 + 2 * q) & 7) << 4));
            const float4 h2 = *(const float4*)(hrow + q * 128 + (((2 + 2 * q) & 7) << 4));
            const float4 h3 = *(const float4*)(hrow + q * 128 + (((3 + 2 * q) & 7) << 4));
            const float4 h4 = *(const float4*)(hrow + q * 128 + (((4 + 2 * q) & 7) << 4));
            const float4 h5 = *(const float4*)(hrow + q * 128 + (((5 + 2 * q) & 7) << 4));
            const float4 h6 = *(const float4*)(hrow + q * 128 + (((6 + 2 * q) & 7) << 4));
            const float4 h7 = *(const float4*)(hrow + q * 128 + (((7 + 2 * q) & 7) << 4));
            const float4 x0 = *(const float4*)(xrow + q * 64 + (((0 + q) & 3) << 4));
            const float4 x1 = *(const float4*)(xrow + q * 64 + (((1 + q) & 3) << 4));
            const float4 x2 = *(const float4*)(xrow + q * 64 + (((2 + q) & 3) << 4));
            const float4 x3 = *(const float4*)(xrow + q * 64 + (((3 + q) & 3) << 4));

            // packed-fp32 dot products, 4 independent accumulators
            v2f a0 = pk_mul(lo4(ar0), lo4(h0));
            v2f a1 = pk_mul(hi4(ar0), hi4(h0));
            v2f a2 = pk_mul(lo4(ar1), lo4(h1));
            v2f a3 = pk_mul(hi4(ar1), hi4(h1));
            a0 = pk_fma(lo4(ar2), lo4(h2), a0);
            a1 = pk_fma(hi4(ar2), hi4(h2), a1);
            a2 = pk_fma(lo4(ar3), lo4(h3), a2);
            a3 = pk_fma(hi4(ar3), hi4(h3), a3);
            a0 = pk_fma(lo4(ar4), lo4(h4), a0);
            a1 = pk_fma(hi4(ar4), hi4(h4), a1);
            a2 = pk_fma(lo4(ar5), lo4(h5), a2);
            a3 = pk_fma(hi4(ar5), hi4(h5), a3);
            a0 = pk_fma(lo4(ar6), lo4(h6), a0);
            a1 = pk_fma(hi4(ar6), hi4(h6), a1);
            a2 = pk_fma(lo4(ar7), lo4(h7), a2);
            a3 = pk_fma(hi4(ar7), hi4(h7), a3);
            a0 = pk_fma(lo4(br0), lo4(x0), a0);
            a1 = pk_fma(hi4(br0), hi4(x0), a1);
            a2 = pk_fma(lo4(br1), lo4(x1), a2);
            a3 = pk_fma(hi4(br1), hi4(x1), a3);
            a0 = pk_fma(lo4(br2), lo4(x2), a0);
            a1 = pk_fma(hi4(br2), hi4(x2), a1);
            a2 = pk_fma(lo4(br3), lo4(x3), a2);
            a3 = pk_fma(hi4(br3), hi4(x3), a3);
            a0 = pk_add(a0, a1);
            a2 = pk_add(a2, a3);
            a0 = pk_add(a0, a2);
            float acc = a0.x + a0.y;

            // quad butterfly via DPP (lanes 4k..4k+3 all end with the full sum)
            acc += dpp_xor1(acc);
            acc += dpp_xor2(acc);

            // tanh(y) = 1 - 2/(2^(K*y) + 1); weights pre-scaled by K => acc is already K*y
            const float yk = acc + bias;
            const float e  = fast_exp2(yk);         // overflow->inf->tanh=1; underflow->0->tanh=-1
            const float th = fmaf(-2.f, fast_rcp(e + 1.f), 1.f);
            if (q == 0) hb[p ^ 1][r] = th;
            __syncthreads();
        }

        // write prefetched chunk into the idle buffer
        if (c + 1 < NCHUNK) {
            float4* d = (float4*)(xs[cur ^ 1]);
            d[0 * NTHR + t] = nx0;
            d[1 * NTHR + t] = nx1;
            d[2 * NTHR + t] = nx2;
            d[3 * NTHR + t] = nx3;
            __syncthreads();
        }
    }

    // ---- epilogue: LayerNorm + head (final h is in hb[0], S even) ----
    if (t < 64) {
        const float a  = hb[0][t];
        const float c2 = hb[0][t + 64];
        float sum = a + c2;
#pragma unroll
        for (int o = 32; o > 0; o >>= 1) sum += __shfl_xor(sum, o);
        const float mu = sum * (1.f / 128.f);
        const float d1 = a - mu, d2 = c2 - mu;
        float sq = d1 * d1 + d2 * d2;
#pragma unroll
        for (int o = 32; o > 0; o >>= 1) sq += __shfl_xor(sq, o);
        const float rs = rsqrtf(sq * (1.f / 128.f) + 1e-5f);
        const float hn1 = d1 * rs * ln_g[t] + ln_b[t];
        const float hn2 = d2 * rs * ln_g[t + 64] + ln_b[t + 64];
        float contrib = hn1 * head_w[t] + hn2 * head_w[t + 64];
#pragma unroll
        for (int o = 32; o > 0; o >>= 1) contrib += __shfl_xor(contrib, o);
        if (t == 0) out[b] = contrib + head_b[0];
    }
}

extern "C" void kernel_launch(void* const* d_in, const int* in_sizes, int n_in,
                              void* d_out, int out_size, void* d_ws, size_t ws_size,
                              hipStream_t stream)
{
    const float* x      = (const float*)d_in[0];
    const float* A_w    = (const float*)d_in[1];
    const float* A_b    = (const float*)d_in[2];
    const float* B_w    = (const float*)d_in[3];
    const float* B_b    = (const float*)d_in[4];
    const float* ln_g   = (const float*)d_in[5];
    const float* ln_b   = (const float*)d_in[6];
    const float* head_w = (const float*)d_in[7];
    const float* head_b = (const float*)d_in[8];
    float* out = (float*)d_out;

    const int Bsz = in_sizes[0] / (S_LEN * I_DIM);  // 256
    nss_scan_kernel<<<Bsz, NTHR, 0, stream>>>(x, A_w, A_b, B_w, B_b,
                                              ln_g, ln_b, head_w, head_b, out);
}